// Round 6
// baseline (818.315 us; speedup 1.0000x reference)
//
#include <hip/hip_runtime.h>

// ---- problem constants ----
#define Hdim   3584
#define NH     28
#define NKV    4
#define HD     128
#define Sq     2048
#define NQKV   4608          // 3584 q + 512 k + 512 v
#define KD     3584          // inner dim of both GEMMs

typedef unsigned short u16;
typedef _Float16 f16;
typedef _Float16 f16x8 __attribute__((ext_vector_type(8)));     // MFMA A/B operand (4 VGPRs)
typedef unsigned short u16x8 __attribute__((ext_vector_type(8)));
typedef float f32x4 __attribute__((ext_vector_type(4)));        // MFMA C/D operand

__device__ __forceinline__ u16 f2h(float x) { f16 h = (f16)x; return __builtin_bit_cast(u16, h); }
__device__ __forceinline__ float h2f(u16 b) { return (float)__builtin_bit_cast(f16, b); }
__device__ __forceinline__ void split2(float x, u16& hi, u16& lo) {
    hi = f2h(x);
    lo = f2h(x - h2f(hi));   // combined ~22-bit mantissa
}

// async global->LDS, 16B per lane; LDS dest = wave-uniform base + lane*16
#define GLL16(gp, lp) __builtin_amdgcn_global_load_lds( \
    (__attribute__((address_space(1))) void*)(gp),      \
    (__attribute__((address_space(3))) void*)(lp), 16, 0, 0)

// ---- fp32 -> fp16, 8 elems/thread ----
__global__ void k_cvt(const float* __restrict__ x, u16* __restrict__ yh, int n8) {
    int i = blockIdx.x * 256 + threadIdx.x;
    if (i >= n8) return;
    const float4* p = (const float4*)(x + (size_t)i * 8);
    float4 a = p[0], b = p[1];
    float v[8] = {a.x, a.y, a.z, a.w, b.x, b.y, b.z, b.w};
    u16x8 h;
#pragma unroll
    for (int j = 0; j < 8; ++j) h[j] = f2h(v[j]);
    *(u16x8*)(yh + (size_t)i * 8) = h;
}

// ---- concat biases (q|k|v) ----
__global__ void k_bias(const float* __restrict__ bq, const float* __restrict__ bk,
                       const float* __restrict__ bv, float* __restrict__ out) {
    int i = blockIdx.x * 256 + threadIdx.x;
    if (i >= NQKV) return;
    out[i] = (i < 3584) ? bq[i] : (i < 4096 ? bk[i - 3584] : bv[i - 4096]);
}

// ---- AWQ int4 dequant -> W (dout x KD) fp16, row-major over output cols ----
__global__ void k_dequant(const int* __restrict__ qw, const int* __restrict__ qz,
                          const float* __restrict__ sc, u16* __restrict__ W, int dout) {
    int idx = blockIdx.x * 256 + threadIdx.x;
    int rb = idx % 448;            // 448 = 3584/8 row-blocks
    int c  = idx / 448;
    if (c >= dout) return;
    int w8 = dout >> 3;
    int j  = c >> 3, sh = (c & 7) << 2;
    int g  = rb >> 4;              // (rb*8)/128  (G=128)
    int z  = (qz[(size_t)g * w8 + j] >> sh) & 15;
    float s = sc[(size_t)g * dout + c];
    int r0 = rb * 8;
    u16x8 v;
#pragma unroll
    for (int i = 0; i < 8; ++i) {
        int w = (qw[(size_t)(r0 + i) * w8 + j] >> sh) & 15;
        v[i] = f2h((float)(w - z) * s);
    }
    *(u16x8*)(W + (size_t)c * KD + r0) = v;
}

// ---- fp16 MFMA GEMM (m97-style): C = A @ B^T + bias, C fp32, optional split-K ----
__global__ __launch_bounds__(256) void k_gemm_f16(const u16* __restrict__ A,
                                                  const u16* __restrict__ B,
                                                  const float* __restrict__ bias,
                                                  float* __restrict__ C,
                                                  float* __restrict__ Cp,
                                                  int M, int N, int K) {
    __shared__ __attribute__((aligned(16))) u16 Ash[128 * 64];
    __shared__ __attribute__((aligned(16))) u16 Bsh[128 * 64];
    int tid = threadIdx.x;
    int m0 = blockIdx.y * 128, n0 = blockIdx.x * 128;
    int klen = K / gridDim.z;
    int kbeg = blockIdx.z * klen, kend = kbeg + klen;
    int wave = tid >> 6, lane = tid & 63;
    int l16 = lane & 15, quad = lane >> 4;
    int wr = wave >> 1, wc = wave & 1;
    int lrow = lane >> 3, lcol = lane & 7;      // staging: 8 rows x 8 chunks(16B)

    f32x4 acc[4][4];
    f32x4 zero4 = {0.f, 0.f, 0.f, 0.f};
#pragma unroll
    for (int i = 0; i < 4; ++i)
#pragma unroll
        for (int j = 0; j < 4; ++j) acc[i][j] = zero4;

    for (int kk = kbeg; kk < kend; kk += 64) {
        __syncthreads();                         // WAR: prior ds_reads done
#pragma unroll
        for (int j = 0; j < 4; ++j) {
            int rbase = wave * 32 + j * 8;       // wave-uniform
            size_t ga = (size_t)(m0 + rbase + lrow) * K + kk + lcol * 8;
            size_t gb = (size_t)(n0 + rbase + lrow) * K + kk + lcol * 8;
            GLL16(A + ga, &Ash[rbase * 64]);
            GLL16(B + gb, &Bsh[rbase * 64]);
        }
        __syncthreads();                         // vmcnt(0) drain -> data visible
#pragma unroll
        for (int kc = 0; kc < 2; ++kc) {
            f16x8 af[4], bv[4];
#pragma unroll
            for (int i = 0; i < 4; ++i)
                af[i] = *(const f16x8*)&Ash[(wr * 64 + i * 16 + l16) * 64 + kc * 32 + quad * 8];
#pragma unroll
            for (int j = 0; j < 4; ++j)
                bv[j] = *(const f16x8*)&Bsh[(wc * 64 + j * 16 + l16) * 64 + kc * 32 + quad * 8];
#pragma unroll
            for (int i = 0; i < 4; ++i)
#pragma unroll
                for (int j = 0; j < 4; ++j)
                    acc[i][j] = __builtin_amdgcn_mfma_f32_16x16x32_f16(af[i], bv[j], acc[i][j], 0, 0, 0);
        }
    }
    float* dst = (blockIdx.z == 0) ? C : Cp;
    bool addb = (bias != nullptr) && (blockIdx.z == 0);
#pragma unroll
    for (int i = 0; i < 4; ++i)
#pragma unroll
        for (int r = 0; r < 4; ++r) {
            int row = m0 + wr * 64 + i * 16 + quad * 4 + r;
#pragma unroll
            for (int j = 0; j < 4; ++j) {
                int col = n0 + wc * 64 + j * 16 + l16;
                float v = acc[i][j][r];
                if (addb) v += bias[col];
                dst[(size_t)row * N + col] = v;
            }
        }
}

// ---- out += partial (fp32, float4) ----
__global__ void k_reduce(float* __restrict__ out, const float* __restrict__ part, int n4) {
    int i = blockIdx.x * 256 + threadIdx.x;
    if (i >= n4) return;
    float4 a = ((const float4*)out)[i];
    float4 b = ((const float4*)part)[i];
    a.x += b.x; a.y += b.y; a.z += b.z; a.w += b.w;
    ((float4*)out)[i] = a;
}

// ---- RoPE (fp64 angles) -> Qh/Ql (S,3584), Kh (S,512) fp16 ----
__global__ void k_rope2(const float* __restrict__ Y, const int* __restrict__ pos,
                        u16* __restrict__ Qh, u16* __restrict__ Ql,
                        u16* __restrict__ Kh) {
    __shared__ double finv[64];
    int tid = threadIdx.x;
    if (tid < 64)   // inv_freq = theta^(-i/64) = 2^(-i*log2(1e6)/64)
        finv[tid] = exp2(-0.3114307588956902 * (double)tid);
    __syncthreads();
    int s = blockIdx.x;
    double p = (double)pos[s];
    const float* y = Y + (size_t)s * NQKV;
    for (int idx = tid; idx < 4096; idx += 256) {
        int d = idx & 127;
        int i = d & 63;
        double ang = p * finv[i];
        double n = rint(ang * 0.15915494309189535);          // /(2*pi)
        float r = (float)fma(-6.283185307179586, n, ang);    // range-reduced angle
        float sn, cs;
        __sincosf(r, &sn, &cs);
        float v  = y[idx];
        float v2 = (d < 64) ? y[idx + 64] : y[idx - 64];
        float o  = (d < 64) ? (v * cs - v2 * sn) : (v * cs + v2 * sn);
        if (idx < 3584) {
            u16 hh, ll;
            split2(o, hh, ll);
            Qh[(size_t)s * 3584 + idx] = hh;
            Ql[(size_t)s * 3584 + idx] = ll;
        } else {
            Kh[(size_t)s * 512 + (idx - 3584)] = f2h(o);
        }
    }
}

// ---- transpose V section of Y: (S x 512) fp32 -> Vt (512 x S) fp16 ----
__global__ __launch_bounds__(256) void k_vtrans(const float* __restrict__ Y,
                                                u16* __restrict__ Vt) {
    __shared__ __attribute__((aligned(16))) u16 T[64][72];
    int s0 = blockIdx.x * 64, d0 = blockIdx.y * 64;
    int tid = threadIdx.x;
#pragma unroll
    for (int t = 0; t < 16; ++t) {
        int idx = tid + t * 256;
        int r = idx >> 6, c = idx & 63;
        T[c][r] = f2h(Y[(size_t)(s0 + r) * NQKV + 4096 + d0 + c]);
    }
    __syncthreads();
#pragma unroll
    for (int t = 0; t < 2; ++t) {
        int cc = tid + t * 256;
        int dr = cc >> 3, s8 = (cc & 7) << 3;
        *(u16x8*)(Vt + (size_t)(d0 + dr) * Sq + s0 + s8) = *(const u16x8*)&T[dr][s8];
    }
}

// ---- barrier-free flash attention: 1 wave per 16-row Q strip ----
// K/V MFMA fragments loaded directly from global (L2-resident); P transform
// via wave-private LDS strip; no __syncthreads anywhere.
__global__ __launch_bounds__(64) void k_attn(const u16* __restrict__ Qh,
                                             const u16* __restrict__ Ql,
                                             const u16* __restrict__ Kh,
                                             const u16* __restrict__ Vt,
                                             u16* __restrict__ AO) {
    __shared__ __attribute__((aligned(16))) u16 Ps[16][72];   // wave-private

    int strip = gridDim.x - 1 - blockIdx.x;   // long strips first
    int h  = blockIdx.y;
    int q0 = strip * 16;
    int kvh = h / 7;                          // NH/NKV = 7
    int lane = threadIdx.x;
    int l16 = lane & 15, quad = lane >> 4;
    const float scale = 0.08838834764831845f;

    // Q fragments hi/lo direct from global (A-layout: m=l16, k=quad*8+j)
    f16x8 qfh[4], qfl[4];
    {
        size_t qoff = (size_t)(q0 + l16) * Hdim + h * HD + quad * 8;
#pragma unroll
        for (int kc = 0; kc < 4; ++kc) {
            qfh[kc] = *(const f16x8*)(Qh + qoff + kc * 32);
            qfl[kc] = *(const f16x8*)(Ql + qoff + kc * 32);
        }
    }

    f32x4 O[8];
    f32x4 zero4 = {0.f, 0.f, 0.f, 0.f};
#pragma unroll
    for (int t = 0; t < 8; ++t) O[t] = zero4;
    float mrow[4], lrow[4];
#pragma unroll
    for (int r = 0; r < 4; ++r) { mrow[r] = -1e30f; lrow[r] = 0.f; }

    const u16* Kbase = Kh + kvh * HD;                  // row stride 512
    const u16* Vbase = Vt + (size_t)(kvh * HD) * Sq;   // row stride Sq

    int ktmax = (q0 + 15) >> 6;
    for (int kt = 0; kt <= ktmax; ++kt) {
        int k0 = kt * 64;

        f32x4 sa[4];                       // S = Q K^T, 2-term split, K from global
#pragma unroll
        for (int ct = 0; ct < 4; ++ct) {
            f32x4 z = zero4;
#pragma unroll
            for (int kc = 0; kc < 4; ++kc) {
                f16x8 b = *(const f16x8*)(Kbase + (size_t)(k0 + ct * 16 + l16) * 512 + kc * 32 + quad * 8);
                z = __builtin_amdgcn_mfma_f32_16x16x32_f16(qfh[kc], b, z, 0, 0, 0);
                z = __builtin_amdgcn_mfma_f32_16x16x32_f16(qfl[kc], b, z, 0, 0, 0);
            }
            sa[ct] = z;
        }
        bool diag = (kt == ktmax);
#pragma unroll
        for (int ct = 0; ct < 4; ++ct)
#pragma unroll
            for (int r = 0; r < 4; ++r) {
                float s = sa[ct][r] * scale;
                if (diag && (k0 + ct * 16 + l16 > q0 + quad * 4 + r)) s = -1e30f;
                sa[ct][r] = s;
            }
        float mnew[4], alpha[4], rs[4];
#pragma unroll
        for (int r = 0; r < 4; ++r) {
            float mx = fmaxf(fmaxf(sa[0][r], sa[1][r]), fmaxf(sa[2][r], sa[3][r]));
#pragma unroll
            for (int off = 1; off < 16; off <<= 1)
                mx = fmaxf(mx, __shfl_xor(mx, off, 64));
            mnew[r] = fmaxf(mrow[r], mx);
            alpha[r] = __expf(mrow[r] - mnew[r]);
            rs[r] = 0.f;
        }
#pragma unroll
        for (int ct = 0; ct < 4; ++ct)
#pragma unroll
            for (int r = 0; r < 4; ++r) {
                float p = __expf(sa[ct][r] - mnew[r]);
                rs[r] += p;
                Ps[quad * 4 + r][ct * 16 + l16] = f2h(p);   // wave-private, lgkm-tracked
            }
#pragma unroll
        for (int r = 0; r < 4; ++r) {
#pragma unroll
            for (int off = 1; off < 16; off <<= 1)
                rs[r] += __shfl_xor(rs[r], off, 64);
            lrow[r] = lrow[r] * alpha[r] + rs[r];
            mrow[r] = mnew[r];
        }
#pragma unroll
        for (int ct = 0; ct < 8; ++ct)
#pragma unroll
            for (int r = 0; r < 4; ++r) O[ct][r] *= alpha[r];
#pragma unroll
        for (int kc = 0; kc < 2; ++kc) {   // P(16x64) @ V^T-frag, V from global
            f16x8 a = *(const f16x8*)&Ps[l16][kc * 32 + quad * 8];
#pragma unroll
            for (int ct = 0; ct < 8; ++ct) {
                f16x8 b = *(const f16x8*)(Vbase + (size_t)(ct * 16 + l16) * Sq + k0 + kc * 32 + quad * 8);
                O[ct] = __builtin_amdgcn_mfma_f32_16x16x32_f16(a, b, O[ct], 0, 0, 0);
            }
        }
    }
#pragma unroll
    for (int r = 0; r < 4; ++r) {
        float inv = 1.f / lrow[r];
        int row = q0 + quad * 4 + r;
#pragma unroll
        for (int ct = 0; ct < 8; ++ct)
            AO[(size_t)row * 3584 + h * HD + ct * 16 + l16] = f2h(O[ct][r] * inv);
    }
}

extern "C" void kernel_launch(void* const* d_in, const int* in_sizes, int n_in,
                              void* d_out, int out_size, void* d_ws, size_t ws_size,
                              hipStream_t stream) {
    (void)in_sizes; (void)n_in; (void)out_size; (void)ws_size;
    const float* hidden = (const float*)d_in[0];
    const int*   pos    = (const int*)d_in[1];
    const int*   qw_q = (const int*)d_in[2];
    const int*   qz_q = (const int*)d_in[3];
    const float* sc_q = (const float*)d_in[4];
    const float* b_q  = (const float*)d_in[5];
    const int*   qw_k = (const int*)d_in[6];
    const int*   qz_k = (const int*)d_in[7];
    const float* sc_k = (const float*)d_in[8];
    const float* b_k  = (const float*)d_in[9];
    const int*   qw_v = (const int*)d_in[10];
    const int*   qz_v = (const int*)d_in[11];
    const float* sc_v = (const float*)d_in[12];
    const float* b_v  = (const float*)d_in[13];
    const int*   qw_o = (const int*)d_in[14];
    const int*   qz_o = (const int*)d_in[15];
    const float* sc_o = (const float*)d_in[16];
    float* out = (float*)d_out;

    char* base = (char*)d_ws;
    size_t off = 0;
    auto alloc = [&](size_t bytes) {
        char* p = base + off;
        off += (bytes + 255) & ~(size_t)255;
        return p;
    };
    u16* Wh = (u16*)alloc((size_t)NQKV * KD * 2);   // 33.0 MB (reused for W_o)
    u16* Xh = (u16*)alloc((size_t)Sq * Hdim * 2);   // 14.7 MB (reused as Qh, then partial)
    u16* Xl = (u16*)alloc((size_t)Sq * Hdim * 2);   // 14.7 MB (Ql, then partial)
    float* Y = (float*)alloc((size_t)Sq * NQKV * 4);// 37.7 MB (reused for AO)
    u16* Khb = (u16*)alloc((size_t)Sq * 512 * 2);   //  2.1 MB
    u16* Vt  = (u16*)alloc((size_t)512 * Sq * 2);   //  2.1 MB
    float* biasc = (float*)alloc(NQKV * 4);
    u16* Qhb = Xh;                 // Xh dead after GEMM1
    u16* Qlb = Xl;
    u16* AO  = (u16*)Y;            // Y dead after rope/vtrans
    u16* Wo  = Wh;                 // Wh dead after GEMM1
    float* Part = (float*)Xh;      // Xh+Xl contiguous = 29.4 MB, dead after attn

    k_cvt<<<3584, 256, 0, stream>>>(hidden, Xh, (Sq * Hdim) / 8);
    k_bias<<<18, 256, 0, stream>>>(b_q, b_k, b_v, biasc);
    k_dequant<<<(3584 * 448) / 256, 256, 0, stream>>>(qw_q, qz_q, sc_q, Wh, 3584);
    k_dequant<<<(512 * 448) / 256, 256, 0, stream>>>(qw_k, qz_k, sc_k, Wh + (size_t)3584 * KD, 512);
    k_dequant<<<(512 * 448) / 256, 256, 0, stream>>>(qw_v, qz_v, sc_v, Wh + (size_t)4096 * KD, 512);
    k_gemm_f16<<<dim3(NQKV / 128, Sq / 128, 1), 256, 0, stream>>>(Xh, Wh, biasc, Y, nullptr, Sq, NQKV, KD);
    k_rope2<<<Sq, 256, 0, stream>>>(Y, pos, Qhb, Qlb, Khb);
    k_vtrans<<<dim3(Sq / 64, 512 / 64), 256, 0, stream>>>(Y, Vt);
    k_dequant<<<(3584 * 448) / 256, 256, 0, stream>>>(qw_o, qz_o, sc_o, Wo, 3584);
    k_attn<<<dim3(Sq / 16, NH), 64, 0, stream>>>(Qhb, Qlb, Khb, Vt, AO);
    k_gemm_f16<<<dim3(Hdim / 128, Sq / 128, 2), 256, 0, stream>>>(AO, Wo, nullptr, out, Part, Sq, Hdim, KD);
    k_reduce<<<(Sq * Hdim / 4 + 255) / 256, 256, 0, stream>>>(out, Part, Sq * Hdim / 4);
}

// Round 7
// 683.841 us; speedup vs baseline: 1.1966x; 1.1966x over previous
//
#include <hip/hip_runtime.h>

// ---- problem constants ----
#define Hdim   3584
#define NH     28
#define NKV    4
#define HD     128
#define Sq     2048
#define NQKV   4608          // 3584 q + 512 k + 512 v
#define KD     3584          // inner dim of both GEMMs

typedef unsigned short u16;
typedef _Float16 f16;
typedef _Float16 f16x8 __attribute__((ext_vector_type(8)));     // MFMA A/B operand (4 VGPRs)
typedef unsigned short u16x8 __attribute__((ext_vector_type(8)));
typedef float f32x4 __attribute__((ext_vector_type(4)));        // MFMA C/D operand

__device__ __forceinline__ u16 f2h(float x) { f16 h = (f16)x; return __builtin_bit_cast(u16, h); }
__device__ __forceinline__ float h2f(u16 b) { return (float)__builtin_bit_cast(f16, b); }
__device__ __forceinline__ void split2(float x, u16& hi, u16& lo) {
    hi = f2h(x);
    lo = f2h(x - h2f(hi));   // combined ~22-bit mantissa
}

// async global->LDS, 16B per lane; LDS dest = wave-uniform base + lane*16
#define GLL16(gp, lp) __builtin_amdgcn_global_load_lds( \
    (__attribute__((address_space(1))) void*)(gp),      \
    (__attribute__((address_space(3))) void*)(lp), 16, 0, 0)

// ---- fp32 -> fp16, 8 elems/thread ----
__global__ void k_cvt(const float* __restrict__ x, u16* __restrict__ yh, int n8) {
    int i = blockIdx.x * 256 + threadIdx.x;
    if (i >= n8) return;
    const float4* p = (const float4*)(x + (size_t)i * 8);
    float4 a = p[0], b = p[1];
    float v[8] = {a.x, a.y, a.z, a.w, b.x, b.y, b.z, b.w};
    u16x8 h;
#pragma unroll
    for (int j = 0; j < 8; ++j) h[j] = f2h(v[j]);
    *(u16x8*)(yh + (size_t)i * 8) = h;
}

// ---- concat biases (q|k|v) ----
__global__ void k_bias(const float* __restrict__ bq, const float* __restrict__ bk,
                       const float* __restrict__ bv, float* __restrict__ out) {
    int i = blockIdx.x * 256 + threadIdx.x;
    if (i >= NQKV) return;
    out[i] = (i < 3584) ? bq[i] : (i < 4096 ? bk[i - 3584] : bv[i - 4096]);
}

// ---- AWQ int4 dequant -> W (dout x KD) fp16, row-major over output cols ----
__global__ void k_dequant(const int* __restrict__ qw, const int* __restrict__ qz,
                          const float* __restrict__ sc, u16* __restrict__ W, int dout) {
    int idx = blockIdx.x * 256 + threadIdx.x;
    int rb = idx % 448;            // 448 = 3584/8 row-blocks
    int c  = idx / 448;
    if (c >= dout) return;
    int w8 = dout >> 3;
    int j  = c >> 3, sh = (c & 7) << 2;
    int g  = rb >> 4;              // (rb*8)/128  (G=128)
    int z  = (qz[(size_t)g * w8 + j] >> sh) & 15;
    float s = sc[(size_t)g * dout + c];
    int r0 = rb * 8;
    u16x8 v;
#pragma unroll
    for (int i = 0; i < 8; ++i) {
        int w = (qw[(size_t)(r0 + i) * w8 + j] >> sh) & 15;
        v[i] = f2h((float)(w - z) * s);
    }
    *(u16x8*)(W + (size_t)c * KD + r0) = v;
}

// ---- fp16 MFMA GEMM (m97-style): C = A @ B^T + bias, C fp32, optional split-K ----
__global__ __launch_bounds__(256) void k_gemm_f16(const u16* __restrict__ A,
                                                  const u16* __restrict__ B,
                                                  const float* __restrict__ bias,
                                                  float* __restrict__ C,
                                                  float* __restrict__ Cp,
                                                  int M, int N, int K) {
    __shared__ __attribute__((aligned(16))) u16 Ash[128 * 64];
    __shared__ __attribute__((aligned(16))) u16 Bsh[128 * 64];
    int tid = threadIdx.x;
    int m0 = blockIdx.y * 128, n0 = blockIdx.x * 128;
    int klen = K / gridDim.z;
    int kbeg = blockIdx.z * klen, kend = kbeg + klen;
    int wave = tid >> 6, lane = tid & 63;
    int l16 = lane & 15, quad = lane >> 4;
    int wr = wave >> 1, wc = wave & 1;
    int lrow = lane >> 3, lcol = lane & 7;      // staging: 8 rows x 8 chunks(16B)

    f32x4 acc[4][4];
    f32x4 zero4 = {0.f, 0.f, 0.f, 0.f};
#pragma unroll
    for (int i = 0; i < 4; ++i)
#pragma unroll
        for (int j = 0; j < 4; ++j) acc[i][j] = zero4;

    for (int kk = kbeg; kk < kend; kk += 64) {
        __syncthreads();                         // WAR: prior ds_reads done
#pragma unroll
        for (int j = 0; j < 4; ++j) {
            int rbase = wave * 32 + j * 8;       // wave-uniform
            size_t ga = (size_t)(m0 + rbase + lrow) * K + kk + lcol * 8;
            size_t gb = (size_t)(n0 + rbase + lrow) * K + kk + lcol * 8;
            GLL16(A + ga, &Ash[rbase * 64]);
            GLL16(B + gb, &Bsh[rbase * 64]);
        }
        __syncthreads();                         // vmcnt(0) drain -> data visible
#pragma unroll
        for (int kc = 0; kc < 2; ++kc) {
            f16x8 af[4], bv[4];
#pragma unroll
            for (int i = 0; i < 4; ++i)
                af[i] = *(const f16x8*)&Ash[(wr * 64 + i * 16 + l16) * 64 + kc * 32 + quad * 8];
#pragma unroll
            for (int j = 0; j < 4; ++j)
                bv[j] = *(const f16x8*)&Bsh[(wc * 64 + j * 16 + l16) * 64 + kc * 32 + quad * 8];
#pragma unroll
            for (int i = 0; i < 4; ++i)
#pragma unroll
                for (int j = 0; j < 4; ++j)
                    acc[i][j] = __builtin_amdgcn_mfma_f32_16x16x32_f16(af[i], bv[j], acc[i][j], 0, 0, 0);
        }
    }
    float* dst = (blockIdx.z == 0) ? C : Cp;
    bool addb = (bias != nullptr) && (blockIdx.z == 0);
#pragma unroll
    for (int i = 0; i < 4; ++i)
#pragma unroll
        for (int r = 0; r < 4; ++r) {
            int row = m0 + wr * 64 + i * 16 + quad * 4 + r;
#pragma unroll
            for (int j = 0; j < 4; ++j) {
                int col = n0 + wc * 64 + j * 16 + l16;
                float v = acc[i][j][r];
                if (addb) v += bias[col];
                dst[(size_t)row * N + col] = v;
            }
        }
}

// ---- out += partial (fp32, float4) ----
__global__ void k_reduce(float* __restrict__ out, const float* __restrict__ part, int n4) {
    int i = blockIdx.x * 256 + threadIdx.x;
    if (i >= n4) return;
    float4 a = ((const float4*)out)[i];
    float4 b = ((const float4*)part)[i];
    a.x += b.x; a.y += b.y; a.z += b.z; a.w += b.w;
    ((float4*)out)[i] = a;
}

// ---- RoPE (fp64 angles) -> Qh/Ql (S,3584), Kh (S,512) fp16 ----
__global__ void k_rope2(const float* __restrict__ Y, const int* __restrict__ pos,
                        u16* __restrict__ Qh, u16* __restrict__ Ql,
                        u16* __restrict__ Kh) {
    __shared__ double finv[64];
    int tid = threadIdx.x;
    if (tid < 64)   // inv_freq = theta^(-i/64) = 2^(-i*log2(1e6)/64)
        finv[tid] = exp2(-0.3114307588956902 * (double)tid);
    __syncthreads();
    int s = blockIdx.x;
    double p = (double)pos[s];
    const float* y = Y + (size_t)s * NQKV;
    for (int idx = tid; idx < 4096; idx += 256) {
        int d = idx & 127;
        int i = d & 63;
        double ang = p * finv[i];
        double n = rint(ang * 0.15915494309189535);          // /(2*pi)
        float r = (float)fma(-6.283185307179586, n, ang);    // range-reduced angle
        float sn, cs;
        __sincosf(r, &sn, &cs);
        float v  = y[idx];
        float v2 = (d < 64) ? y[idx + 64] : y[idx - 64];
        float o  = (d < 64) ? (v * cs - v2 * sn) : (v * cs + v2 * sn);
        if (idx < 3584) {
            u16 hh, ll;
            split2(o, hh, ll);
            Qh[(size_t)s * 3584 + idx] = hh;
            Ql[(size_t)s * 3584 + idx] = ll;
        } else {
            Kh[(size_t)s * 512 + (idx - 3584)] = f2h(o);
        }
    }
}

// ---- transpose V section of Y: (S x 512) fp32 -> Vt (512 x S) fp16 ----
__global__ __launch_bounds__(256) void k_vtrans(const float* __restrict__ Y,
                                                u16* __restrict__ Vt) {
    __shared__ __attribute__((aligned(16))) u16 T[64][72];
    int s0 = blockIdx.x * 64, d0 = blockIdx.y * 64;
    int tid = threadIdx.x;
#pragma unroll
    for (int t = 0; t < 16; ++t) {
        int idx = tid + t * 256;
        int r = idx >> 6, c = idx & 63;
        T[c][r] = f2h(Y[(size_t)(s0 + r) * NQKV + 4096 + d0 + c]);
    }
    __syncthreads();
#pragma unroll
    for (int t = 0; t < 2; ++t) {
        int cc = tid + t * 256;
        int dr = cc >> 3, s8 = (cc & 7) << 3;
        *(u16x8*)(Vt + (size_t)(d0 + dr) * Sq + s0 + s8) = *(const u16x8*)&T[dr][s8];
    }
}

// ---- flash attention fp16, 2-term QK^T: 64-row Q tile, 4 waves x 16 rows ----
// Register-prefetch pipeline: next K/V tile loaded to VGPRs during compute,
// committed to LDS after the compute barrier. Padded LDS (2-way max).
__global__ __launch_bounds__(256) void k_attn(const u16* __restrict__ Qh,
                                              const u16* __restrict__ Ql,
                                              const u16* __restrict__ Kh,
                                              const u16* __restrict__ Vt,
                                              u16* __restrict__ AO) {
    __shared__ __attribute__((aligned(16))) u16 Ks[64][136];
    __shared__ __attribute__((aligned(16))) u16 Vs[128][72];   // V^T tile: d x key
    __shared__ __attribute__((aligned(16))) u16 Ps[4][16][72]; // per-wave P strip

    int qt = gridDim.x - 1 - blockIdx.x;   // big tiles first (tail balance)
    int h  = blockIdx.y;
    int q0 = qt * 64;
    int kvh = h / 7;                       // NH/NKV = 7
    int tid = threadIdx.x;
    int wave = tid >> 6, lane = tid & 63, l16 = lane & 15, quad = lane >> 4;
    const float scale = 0.08838834764831845f;

    const u16* Kbase = Kh + kvh * HD;                  // row stride 512
    const u16* Vbase = Vt + (size_t)(kvh * HD) * Sq;   // row stride Sq

    // Q fragments hi/lo direct from global (A-layout: m=l16, k=quad*8+j)
    f16x8 qfh[4], qfl[4];
    {
        size_t qoff = (size_t)(q0 + wave * 16 + l16) * Hdim + h * HD + quad * 8;
#pragma unroll
        for (int kc = 0; kc < 4; ++kc) {
            qfh[kc] = *(const f16x8*)(Qh + qoff + kc * 32);
            qfl[kc] = *(const f16x8*)(Ql + qoff + kc * 32);
        }
    }

    // initial staging of tile 0 (load -> LDS -> barrier)
    {
#pragma unroll
        for (int t = 0; t < 4; ++t) {
            int c = tid + t * 256;
            int row = c >> 4, s8 = (c & 15) << 3;
            *(u16x8*)&Ks[row][s8] = *(const u16x8*)(Kbase + (size_t)row * 512 + s8);
        }
#pragma unroll
        for (int t = 0; t < 4; ++t) {
            int c = tid + t * 256;
            int d = c >> 3, k8 = (c & 7) << 3;
            *(u16x8*)&Vs[d][k8] = *(const u16x8*)(Vbase + (size_t)d * Sq + k8);
        }
        __syncthreads();
    }

    f32x4 O[8];
    f32x4 zero4 = {0.f, 0.f, 0.f, 0.f};
#pragma unroll
    for (int t = 0; t < 8; ++t) O[t] = zero4;
    float mrow[4], lrow[4];
#pragma unroll
    for (int r = 0; r < 4; ++r) { mrow[r] = -1e30f; lrow[r] = 0.f; }

    for (int kt = 0; kt <= qt; ++kt) {
        int k0 = kt * 64;
        int kn = (kt < qt) ? k0 + 64 : k0;     // clamped prefetch base

        // ---- issue next-tile loads into registers (latency overlapped) ----
        u16x8 nk[4], nv[4];
#pragma unroll
        for (int t = 0; t < 4; ++t) {
            int c = tid + t * 256;
            nk[t] = *(const u16x8*)(Kbase + (size_t)(kn + (c >> 4)) * 512 + ((c & 15) << 3));
            nv[t] = *(const u16x8*)(Vbase + (size_t)(c >> 3) * Sq + kn + ((c & 7) << 3));
        }

        // ---- compute current tile from LDS ----
        f32x4 sa[4];                       // S = Q K^T, 2-term split
#pragma unroll
        for (int ct = 0; ct < 4; ++ct) {
            f32x4 z = zero4;
#pragma unroll
            for (int kc = 0; kc < 4; ++kc) {
                f16x8 b = *(const f16x8*)&Ks[ct * 16 + l16][kc * 32 + quad * 8];
                z = __builtin_amdgcn_mfma_f32_16x16x32_f16(qfh[kc], b, z, 0, 0, 0);
                z = __builtin_amdgcn_mfma_f32_16x16x32_f16(qfl[kc], b, z, 0, 0, 0);
            }
            sa[ct] = z;
        }
        bool diag = (kt == qt);
#pragma unroll
        for (int ct = 0; ct < 4; ++ct)
#pragma unroll
            for (int r = 0; r < 4; ++r) {
                float s = sa[ct][r] * scale;
                if (diag && (k0 + ct * 16 + l16 > q0 + wave * 16 + quad * 4 + r)) s = -1e30f;
                sa[ct][r] = s;
            }
        float mnew[4], alpha[4], rs[4];
#pragma unroll
        for (int r = 0; r < 4; ++r) {
            float mx = fmaxf(fmaxf(sa[0][r], sa[1][r]), fmaxf(sa[2][r], sa[3][r]));
#pragma unroll
            for (int off = 1; off < 16; off <<= 1)
                mx = fmaxf(mx, __shfl_xor(mx, off, 64));
            mnew[r] = fmaxf(mrow[r], mx);
            alpha[r] = __expf(mrow[r] - mnew[r]);
            rs[r] = 0.f;
        }
#pragma unroll
        for (int ct = 0; ct < 4; ++ct)
#pragma unroll
            for (int r = 0; r < 4; ++r) {
                float p = __expf(sa[ct][r] - mnew[r]);
                rs[r] += p;
                Ps[wave][quad * 4 + r][ct * 16 + l16] = f2h(p);
            }
#pragma unroll
        for (int r = 0; r < 4; ++r) {
#pragma unroll
            for (int off = 1; off < 16; off <<= 1)
                rs[r] += __shfl_xor(rs[r], off, 64);
            lrow[r] = lrow[r] * alpha[r] + rs[r];
            mrow[r] = mnew[r];
        }
#pragma unroll
        for (int ct = 0; ct < 8; ++ct)
#pragma unroll
            for (int r = 0; r < 4; ++r) O[ct][r] *= alpha[r];
#pragma unroll
        for (int kc = 0; kc < 2; ++kc) {   // PV from LDS (Ps wave-private)
            f16x8 a = *(const f16x8*)&Ps[wave][l16][kc * 32 + quad * 8];
#pragma unroll
            for (int ct = 0; ct < 8; ++ct) {
                f16x8 b = *(const f16x8*)&Vs[ct * 16 + l16][kc * 32 + quad * 8];
                O[ct] = __builtin_amdgcn_mfma_f32_16x16x32_f16(a, b, O[ct], 0, 0, 0);
            }
        }

        // ---- commit prefetched tile to LDS ----
        __syncthreads();                   // all waves done reading Ks/Vs
#pragma unroll
        for (int t = 0; t < 4; ++t) {
            int c = tid + t * 256;
            *(u16x8*)&Ks[c >> 4][(c & 15) << 3] = nk[t];
            *(u16x8*)&Vs[c >> 3][(c & 7) << 3]  = nv[t];
        }
        __syncthreads();                   // staged data visible
    }
#pragma unroll
    for (int r = 0; r < 4; ++r) {
        float inv = 1.f / lrow[r];
        int row = q0 + wave * 16 + quad * 4 + r;
#pragma unroll
        for (int ct = 0; ct < 8; ++ct)
            AO[(size_t)row * 3584 + h * HD + ct * 16 + l16] = f2h(O[ct][r] * inv);
    }
}

extern "C" void kernel_launch(void* const* d_in, const int* in_sizes, int n_in,
                              void* d_out, int out_size, void* d_ws, size_t ws_size,
                              hipStream_t stream) {
    (void)in_sizes; (void)n_in; (void)out_size; (void)ws_size;
    const float* hidden = (const float*)d_in[0];
    const int*   pos    = (const int*)d_in[1];
    const int*   qw_q = (const int*)d_in[2];
    const int*   qz_q = (const int*)d_in[3];
    const float* sc_q = (const float*)d_in[4];
    const float* b_q  = (const float*)d_in[5];
    const int*   qw_k = (const int*)d_in[6];
    const int*   qz_k = (const int*)d_in[7];
    const float* sc_k = (const float*)d_in[8];
    const float* b_k  = (const float*)d_in[9];
    const int*   qw_v = (const int*)d_in[10];
    const int*   qz_v = (const int*)d_in[11];
    const float* sc_v = (const float*)d_in[12];
    const float* b_v  = (const float*)d_in[13];
    const int*   qw_o = (const int*)d_in[14];
    const int*   qz_o = (const int*)d_in[15];
    const float* sc_o = (const float*)d_in[16];
    float* out = (float*)d_out;

    char* base = (char*)d_ws;
    size_t off = 0;
    auto alloc = [&](size_t bytes) {
        char* p = base + off;
        off += (bytes + 255) & ~(size_t)255;
        return p;
    };
    u16* Wh = (u16*)alloc((size_t)NQKV * KD * 2);   // 33.0 MB (reused for W_o)
    u16* Xh = (u16*)alloc((size_t)Sq * Hdim * 2);   // 14.7 MB (reused as Qh, then partial)
    u16* Xl = (u16*)alloc((size_t)Sq * Hdim * 2);   // 14.7 MB (Ql, then partial)
    float* Y = (float*)alloc((size_t)Sq * NQKV * 4);// 37.7 MB (reused for AO)
    u16* Khb = (u16*)alloc((size_t)Sq * 512 * 2);   //  2.1 MB
    u16* Vt  = (u16*)alloc((size_t)512 * Sq * 2);   //  2.1 MB
    float* biasc = (float*)alloc(NQKV * 4);
    u16* Qhb = Xh;                 // Xh dead after GEMM1
    u16* Qlb = Xl;
    u16* AO  = (u16*)Y;            // Y dead after rope/vtrans
    u16* Wo  = Wh;                 // Wh dead after GEMM1
    float* Part = (float*)Xh;      // Xh+Xl contiguous = 29.4 MB, dead after attn

    k_cvt<<<3584, 256, 0, stream>>>(hidden, Xh, (Sq * Hdim) / 8);
    k_bias<<<18, 256, 0, stream>>>(b_q, b_k, b_v, biasc);
    k_dequant<<<(3584 * 448) / 256, 256, 0, stream>>>(qw_q, qz_q, sc_q, Wh, 3584);
    k_dequant<<<(512 * 448) / 256, 256, 0, stream>>>(qw_k, qz_k, sc_k, Wh + (size_t)3584 * KD, 512);
    k_dequant<<<(512 * 448) / 256, 256, 0, stream>>>(qw_v, qz_v, sc_v, Wh + (size_t)4096 * KD, 512);
    k_gemm_f16<<<dim3(NQKV / 128, Sq / 128, 1), 256, 0, stream>>>(Xh, Wh, biasc, Y, nullptr, Sq, NQKV, KD);
    k_rope2<<<Sq, 256, 0, stream>>>(Y, pos, Qhb, Qlb, Khb);
    k_vtrans<<<dim3(Sq / 64, 512 / 64), 256, 0, stream>>>(Y, Vt);
    k_dequant<<<(3584 * 448) / 256, 256, 0, stream>>>(qw_o, qz_o, sc_o, Wo, 3584);
    k_attn<<<dim3(Sq / 64, NH), 256, 0, stream>>>(Qhb, Qlb, Khb, Vt, AO);
    k_gemm_f16<<<dim3(Hdim / 128, Sq / 128, 2), 256, 0, stream>>>(AO, Wo, nullptr, out, Part, Sq, Hdim, KD);
    k_reduce<<<(Sq * Hdim / 4 + 255) / 256, 256, 0, stream>>>(out, Part, Sq * Hdim / 4);
}

// Round 8
// 627.298 us; speedup vs baseline: 1.3045x; 1.0901x over previous
//
#include <hip/hip_runtime.h>

// ---- problem constants ----
#define Hdim   3584
#define NH     28
#define NKV    4
#define HD     128
#define Sq     2048
#define NQKV   4608          // 3584 q + 512 k + 512 v
#define KD     3584          // inner dim of both GEMMs

typedef unsigned short u16;
typedef _Float16 f16;
typedef _Float16 f16x8 __attribute__((ext_vector_type(8)));     // MFMA A/B operand (4 VGPRs)
typedef unsigned short u16x8 __attribute__((ext_vector_type(8)));
typedef float f32x4 __attribute__((ext_vector_type(4)));        // MFMA C/D operand

__device__ __forceinline__ u16 f2h(float x) { f16 h = (f16)x; return __builtin_bit_cast(u16, h); }
__device__ __forceinline__ float h2f(u16 b) { return (float)__builtin_bit_cast(f16, b); }
__device__ __forceinline__ void split2(float x, u16& hi, u16& lo) {
    hi = f2h(x);
    lo = f2h(x - h2f(hi));   // combined ~22-bit mantissa
}

// async global->LDS, 16B per lane; LDS dest = wave-uniform base + lane*16
#define GLL16(gp, lp) __builtin_amdgcn_global_load_lds( \
    (__attribute__((address_space(1))) void*)(gp),      \
    (__attribute__((address_space(3))) void*)(lp), 16, 0, 0)

// ---- fp32 -> fp16, 8 elems/thread ----
__global__ void k_cvt(const float* __restrict__ x, u16* __restrict__ yh, int n8) {
    int i = blockIdx.x * 256 + threadIdx.x;
    if (i >= n8) return;
    const float4* p = (const float4*)(x + (size_t)i * 8);
    float4 a = p[0], b = p[1];
    float v[8] = {a.x, a.y, a.z, a.w, b.x, b.y, b.z, b.w};
    u16x8 h;
#pragma unroll
    for (int j = 0; j < 8; ++j) h[j] = f2h(v[j]);
    *(u16x8*)(yh + (size_t)i * 8) = h;
}

// ---- concat biases (q|k|v) ----
__global__ void k_bias(const float* __restrict__ bq, const float* __restrict__ bk,
                       const float* __restrict__ bv, float* __restrict__ out) {
    int i = blockIdx.x * 256 + threadIdx.x;
    if (i >= NQKV) return;
    out[i] = (i < 3584) ? bq[i] : (i < 4096 ? bk[i - 3584] : bv[i - 4096]);
}

// ---- AWQ int4 dequant -> W (dout x KD) fp16, row-major over output cols ----
__global__ void k_dequant(const int* __restrict__ qw, const int* __restrict__ qz,
                          const float* __restrict__ sc, u16* __restrict__ W, int dout) {
    int idx = blockIdx.x * 256 + threadIdx.x;
    int rb = idx % 448;            // 448 = 3584/8 row-blocks
    int c  = idx / 448;
    if (c >= dout) return;
    int w8 = dout >> 3;
    int j  = c >> 3, sh = (c & 7) << 2;
    int g  = rb >> 4;              // (rb*8)/128  (G=128)
    int z  = (qz[(size_t)g * w8 + j] >> sh) & 15;
    float s = sc[(size_t)g * dout + c];
    int r0 = rb * 8;
    u16x8 v;
#pragma unroll
    for (int i = 0; i < 8; ++i) {
        int w = (qw[(size_t)(r0 + i) * w8 + j] >> sh) & 15;
        v[i] = f2h((float)(w - z) * s);
    }
    *(u16x8*)(W + (size_t)c * KD + r0) = v;
}

// ---- fp16 MFMA GEMM (m97-style): C = A @ B^T + bias, C fp32, optional split-K ----
__global__ __launch_bounds__(256) void k_gemm_f16(const u16* __restrict__ A,
                                                  const u16* __restrict__ B,
                                                  const float* __restrict__ bias,
                                                  float* __restrict__ C,
                                                  float* __restrict__ Cp,
                                                  int M, int N, int K) {
    __shared__ __attribute__((aligned(16))) u16 Ash[128 * 64];
    __shared__ __attribute__((aligned(16))) u16 Bsh[128 * 64];
    int tid = threadIdx.x;
    int m0 = blockIdx.y * 128, n0 = blockIdx.x * 128;
    int klen = K / gridDim.z;
    int kbeg = blockIdx.z * klen, kend = kbeg + klen;
    int wave = tid >> 6, lane = tid & 63;
    int l16 = lane & 15, quad = lane >> 4;
    int wr = wave >> 1, wc = wave & 1;
    int lrow = lane >> 3, lcol = lane & 7;      // staging: 8 rows x 8 chunks(16B)

    f32x4 acc[4][4];
    f32x4 zero4 = {0.f, 0.f, 0.f, 0.f};
#pragma unroll
    for (int i = 0; i < 4; ++i)
#pragma unroll
        for (int j = 0; j < 4; ++j) acc[i][j] = zero4;

    for (int kk = kbeg; kk < kend; kk += 64) {
        __syncthreads();                         // WAR: prior ds_reads done
#pragma unroll
        for (int j = 0; j < 4; ++j) {
            int rbase = wave * 32 + j * 8;       // wave-uniform
            size_t ga = (size_t)(m0 + rbase + lrow) * K + kk + lcol * 8;
            size_t gb = (size_t)(n0 + rbase + lrow) * K + kk + lcol * 8;
            GLL16(A + ga, &Ash[rbase * 64]);
            GLL16(B + gb, &Bsh[rbase * 64]);
        }
        __syncthreads();                         // vmcnt(0) drain -> data visible
#pragma unroll
        for (int kc = 0; kc < 2; ++kc) {
            f16x8 af[4], bv[4];
#pragma unroll
            for (int i = 0; i < 4; ++i)
                af[i] = *(const f16x8*)&Ash[(wr * 64 + i * 16 + l16) * 64 + kc * 32 + quad * 8];
#pragma unroll
            for (int j = 0; j < 4; ++j)
                bv[j] = *(const f16x8*)&Bsh[(wc * 64 + j * 16 + l16) * 64 + kc * 32 + quad * 8];
#pragma unroll
            for (int i = 0; i < 4; ++i)
#pragma unroll
                for (int j = 0; j < 4; ++j)
                    acc[i][j] = __builtin_amdgcn_mfma_f32_16x16x32_f16(af[i], bv[j], acc[i][j], 0, 0, 0);
        }
    }
    float* dst = (blockIdx.z == 0) ? C : Cp;
    bool addb = (bias != nullptr) && (blockIdx.z == 0);
#pragma unroll
    for (int i = 0; i < 4; ++i)
#pragma unroll
        for (int r = 0; r < 4; ++r) {
            int row = m0 + wr * 64 + i * 16 + quad * 4 + r;
#pragma unroll
            for (int j = 0; j < 4; ++j) {
                int col = n0 + wc * 64 + j * 16 + l16;
                float v = acc[i][j][r];
                if (addb) v += bias[col];
                dst[(size_t)row * N + col] = v;
            }
        }
}

// ---- out += partial (fp32, float4) ----
__global__ void k_reduce(float* __restrict__ out, const float* __restrict__ part, int n4) {
    int i = blockIdx.x * 256 + threadIdx.x;
    if (i >= n4) return;
    float4 a = ((const float4*)out)[i];
    float4 b = ((const float4*)part)[i];
    a.x += b.x; a.y += b.y; a.z += b.z; a.w += b.w;
    ((float4*)out)[i] = a;
}

// ---- RoPE (fp64 angles) -> Qh/Ql (S,3584), Kh (S,512) fp16 ----
__global__ void k_rope2(const float* __restrict__ Y, const int* __restrict__ pos,
                        u16* __restrict__ Qh, u16* __restrict__ Ql,
                        u16* __restrict__ Kh) {
    __shared__ double finv[64];
    int tid = threadIdx.x;
    if (tid < 64)   // inv_freq = theta^(-i/64) = 2^(-i*log2(1e6)/64)
        finv[tid] = exp2(-0.3114307588956902 * (double)tid);
    __syncthreads();
    int s = blockIdx.x;
    double p = (double)pos[s];
    const float* y = Y + (size_t)s * NQKV;
    for (int idx = tid; idx < 4096; idx += 256) {
        int d = idx & 127;
        int i = d & 63;
        double ang = p * finv[i];
        double n = rint(ang * 0.15915494309189535);          // /(2*pi)
        float r = (float)fma(-6.283185307179586, n, ang);    // range-reduced angle
        float sn, cs;
        __sincosf(r, &sn, &cs);
        float v  = y[idx];
        float v2 = (d < 64) ? y[idx + 64] : y[idx - 64];
        float o  = (d < 64) ? (v * cs - v2 * sn) : (v * cs + v2 * sn);
        if (idx < 3584) {
            u16 hh, ll;
            split2(o, hh, ll);
            Qh[(size_t)s * 3584 + idx] = hh;
            Ql[(size_t)s * 3584 + idx] = ll;
        } else {
            Kh[(size_t)s * 512 + (idx - 3584)] = f2h(o);
        }
    }
}

// ---- transpose V section of Y: (S x 512) fp32 -> Vt (512 x S) fp16 ----
__global__ __launch_bounds__(256) void k_vtrans(const float* __restrict__ Y,
                                                u16* __restrict__ Vt) {
    __shared__ __attribute__((aligned(16))) u16 T[64][72];
    int s0 = blockIdx.x * 64, d0 = blockIdx.y * 64;
    int tid = threadIdx.x;
#pragma unroll
    for (int t = 0; t < 16; ++t) {
        int idx = tid + t * 256;
        int r = idx >> 6, c = idx & 63;
        T[c][r] = f2h(Y[(size_t)(s0 + r) * NQKV + 4096 + d0 + c]);
    }
    __syncthreads();
#pragma unroll
    for (int t = 0; t < 2; ++t) {
        int cc = tid + t * 256;
        int dr = cc >> 3, s8 = (cc & 7) << 3;
        *(u16x8*)(Vt + (size_t)(d0 + dr) * Sq + s0 + s8) = *(const u16x8*)&T[dr][s8];
    }
}

// ---- flash attention fp16: persistent blocks, LPT dynamic queue ----
// 768 blocks (= 3/CU LDS cap) pull (head, qt) items from a global counter,
// longest items (qt=31) first -> near-zero drain tail. Per-item body: 64-row
// Q tile, 4 waves x 16 rows, register-prefetch K/V pipeline, padded LDS.
__global__ __launch_bounds__(256) void k_attn(const u16* __restrict__ Qh,
                                              const u16* __restrict__ Ql,
                                              const u16* __restrict__ Kh,
                                              const u16* __restrict__ Vt,
                                              u16* __restrict__ AO,
                                              int* __restrict__ ctr) {
    __shared__ __attribute__((aligned(16))) u16 Ks[64][136];
    __shared__ __attribute__((aligned(16))) u16 Vs[128][72];   // V^T tile: d x key
    __shared__ __attribute__((aligned(16))) u16 Ps[4][16][72]; // per-wave P strip
    __shared__ int s_item;

    int tid = threadIdx.x;
    int wave = tid >> 6, lane = tid & 63, l16 = lane & 15, quad = lane >> 4;
    const float scale = 0.08838834764831845f;

    for (;;) {
        __syncthreads();                   // all waves done with prior item + s_item
        if (tid == 0) s_item = atomicAdd(ctr, 1);
        __syncthreads();
        int item = s_item;
        if (item >= 32 * NH) break;        // block-uniform exit
        int qt = 31 - item / NH;           // longest first (LPT)
        int h  = item % NH;
        int q0 = qt * 64;
        int kvh = h / 7;                   // NH/NKV = 7

        const u16* Kbase = Kh + kvh * HD;                  // row stride 512
        const u16* Vbase = Vt + (size_t)(kvh * HD) * Sq;   // row stride Sq

        // Q fragments hi/lo direct from global (A-layout: m=l16, k=quad*8+j)
        f16x8 qfh[4], qfl[4];
        {
            size_t qoff = (size_t)(q0 + wave * 16 + l16) * Hdim + h * HD + quad * 8;
#pragma unroll
            for (int kc = 0; kc < 4; ++kc) {
                qfh[kc] = *(const f16x8*)(Qh + qoff + kc * 32);
                qfl[kc] = *(const f16x8*)(Ql + qoff + kc * 32);
            }
        }

        // initial staging of tile 0
#pragma unroll
        for (int t = 0; t < 4; ++t) {
            int c = tid + t * 256;
            int row = c >> 4, s8 = (c & 15) << 3;
            *(u16x8*)&Ks[row][s8] = *(const u16x8*)(Kbase + (size_t)row * 512 + s8);
        }
#pragma unroll
        for (int t = 0; t < 4; ++t) {
            int c = tid + t * 256;
            int d = c >> 3, k8 = (c & 7) << 3;
            *(u16x8*)&Vs[d][k8] = *(const u16x8*)(Vbase + (size_t)d * Sq + k8);
        }
        __syncthreads();

        f32x4 O[8];
        f32x4 zero4 = {0.f, 0.f, 0.f, 0.f};
#pragma unroll
        for (int t = 0; t < 8; ++t) O[t] = zero4;
        float mrow[4], lrow[4];
#pragma unroll
        for (int r = 0; r < 4; ++r) { mrow[r] = -1e30f; lrow[r] = 0.f; }

        for (int kt = 0; kt <= qt; ++kt) {
            int k0 = kt * 64;
            int kn = (kt < qt) ? k0 + 64 : k0;     // clamped prefetch base

            // ---- issue next-tile loads into registers (latency overlapped) ----
            u16x8 nk[4], nv[4];
#pragma unroll
            for (int t = 0; t < 4; ++t) {
                int c = tid + t * 256;
                nk[t] = *(const u16x8*)(Kbase + (size_t)(kn + (c >> 4)) * 512 + ((c & 15) << 3));
                nv[t] = *(const u16x8*)(Vbase + (size_t)(c >> 3) * Sq + kn + ((c & 7) << 3));
            }

            // ---- compute current tile from LDS ----
            f32x4 sa[4];                       // S = Q K^T, 2-term split
#pragma unroll
            for (int ct = 0; ct < 4; ++ct) {
                f32x4 z = zero4;
#pragma unroll
                for (int kc = 0; kc < 4; ++kc) {
                    f16x8 b = *(const f16x8*)&Ks[ct * 16 + l16][kc * 32 + quad * 8];
                    z = __builtin_amdgcn_mfma_f32_16x16x32_f16(qfh[kc], b, z, 0, 0, 0);
                    z = __builtin_amdgcn_mfma_f32_16x16x32_f16(qfl[kc], b, z, 0, 0, 0);
                }
                sa[ct] = z;
            }
            bool diag = (kt == qt);
#pragma unroll
            for (int ct = 0; ct < 4; ++ct)
#pragma unroll
                for (int r = 0; r < 4; ++r) {
                    float s = sa[ct][r] * scale;
                    if (diag && (k0 + ct * 16 + l16 > q0 + wave * 16 + quad * 4 + r)) s = -1e30f;
                    sa[ct][r] = s;
                }
            float mnew[4], alpha[4], rs[4];
#pragma unroll
            for (int r = 0; r < 4; ++r) {
                float mx = fmaxf(fmaxf(sa[0][r], sa[1][r]), fmaxf(sa[2][r], sa[3][r]));
#pragma unroll
                for (int off = 1; off < 16; off <<= 1)
                    mx = fmaxf(mx, __shfl_xor(mx, off, 64));
                mnew[r] = fmaxf(mrow[r], mx);
                alpha[r] = __expf(mrow[r] - mnew[r]);
                rs[r] = 0.f;
            }
#pragma unroll
            for (int ct = 0; ct < 4; ++ct)
#pragma unroll
                for (int r = 0; r < 4; ++r) {
                    float p = __expf(sa[ct][r] - mnew[r]);
                    rs[r] += p;
                    Ps[wave][quad * 4 + r][ct * 16 + l16] = f2h(p);
                }
#pragma unroll
            for (int r = 0; r < 4; ++r) {
#pragma unroll
                for (int off = 1; off < 16; off <<= 1)
                    rs[r] += __shfl_xor(rs[r], off, 64);
                lrow[r] = lrow[r] * alpha[r] + rs[r];
                mrow[r] = mnew[r];
            }
#pragma unroll
            for (int ct = 0; ct < 8; ++ct)
#pragma unroll
                for (int r = 0; r < 4; ++r) O[ct][r] *= alpha[r];
#pragma unroll
            for (int kc = 0; kc < 2; ++kc) {   // PV from LDS (Ps wave-private)
                f16x8 a = *(const f16x8*)&Ps[wave][l16][kc * 32 + quad * 8];
#pragma unroll
                for (int ct = 0; ct < 8; ++ct) {
                    f16x8 b = *(const f16x8*)&Vs[ct * 16 + l16][kc * 32 + quad * 8];
                    O[ct] = __builtin_amdgcn_mfma_f32_16x16x32_f16(a, b, O[ct], 0, 0, 0);
                }
            }

            // ---- commit prefetched tile to LDS ----
            __syncthreads();                   // all waves done reading Ks/Vs
#pragma unroll
            for (int t = 0; t < 4; ++t) {
                int c = tid + t * 256;
                *(u16x8*)&Ks[c >> 4][(c & 15) << 3] = nk[t];
                *(u16x8*)&Vs[c >> 3][(c & 7) << 3]  = nv[t];
            }
            __syncthreads();                   // staged data visible
        }
#pragma unroll
        for (int r = 0; r < 4; ++r) {
            float inv = 1.f / lrow[r];
            int row = q0 + wave * 16 + quad * 4 + r;
#pragma unroll
            for (int ct = 0; ct < 8; ++ct)
                AO[(size_t)row * 3584 + h * HD + ct * 16 + l16] = f2h(O[ct][r] * inv);
        }
    }
}

extern "C" void kernel_launch(void* const* d_in, const int* in_sizes, int n_in,
                              void* d_out, int out_size, void* d_ws, size_t ws_size,
                              hipStream_t stream) {
    (void)in_sizes; (void)n_in; (void)out_size; (void)ws_size;
    const float* hidden = (const float*)d_in[0];
    const int*   pos    = (const int*)d_in[1];
    const int*   qw_q = (const int*)d_in[2];
    const int*   qz_q = (const int*)d_in[3];
    const float* sc_q = (const float*)d_in[4];
    const float* b_q  = (const float*)d_in[5];
    const int*   qw_k = (const int*)d_in[6];
    const int*   qz_k = (const int*)d_in[7];
    const float* sc_k = (const float*)d_in[8];
    const float* b_k  = (const float*)d_in[9];
    const int*   qw_v = (const int*)d_in[10];
    const int*   qz_v = (const int*)d_in[11];
    const float* sc_v = (const float*)d_in[12];
    const float* b_v  = (const float*)d_in[13];
    const int*   qw_o = (const int*)d_in[14];
    const int*   qz_o = (const int*)d_in[15];
    const float* sc_o = (const float*)d_in[16];
    float* out = (float*)d_out;

    char* base = (char*)d_ws;
    size_t off = 0;
    auto alloc = [&](size_t bytes) {
        char* p = base + off;
        off += (bytes + 255) & ~(size_t)255;
        return p;
    };
    u16* Wh = (u16*)alloc((size_t)NQKV * KD * 2);   // 33.0 MB (reused for W_o)
    u16* Xh = (u16*)alloc((size_t)Sq * Hdim * 2);   // 14.7 MB (reused as Qh, then partial)
    u16* Xl = (u16*)alloc((size_t)Sq * Hdim * 2);   // 14.7 MB (Ql, then partial)
    float* Y = (float*)alloc((size_t)Sq * NQKV * 4);// 37.7 MB (reused for AO)
    u16* Khb = (u16*)alloc((size_t)Sq * 512 * 2);   //  2.1 MB
    u16* Vt  = (u16*)alloc((size_t)512 * Sq * 2);   //  2.1 MB
    float* biasc = (float*)alloc(NQKV * 4);
    int*   ctr   = (int*)alloc(256);                // attn work-queue counter
    u16* Qhb = Xh;                 // Xh dead after GEMM1
    u16* Qlb = Xl;
    u16* AO  = (u16*)Y;            // Y dead after rope/vtrans
    u16* Wo  = Wh;                 // Wh dead after GEMM1
    float* Part = (float*)Xh;      // Xh+Xl contiguous = 29.4 MB, dead after attn

    hipMemsetAsync(ctr, 0, sizeof(int), stream);    // ws is re-poisoned each call
    k_cvt<<<3584, 256, 0, stream>>>(hidden, Xh, (Sq * Hdim) / 8);
    k_bias<<<18, 256, 0, stream>>>(b_q, b_k, b_v, biasc);
    k_dequant<<<(3584 * 448) / 256, 256, 0, stream>>>(qw_q, qz_q, sc_q, Wh, 3584);
    k_dequant<<<(512 * 448) / 256, 256, 0, stream>>>(qw_k, qz_k, sc_k, Wh + (size_t)3584 * KD, 512);
    k_dequant<<<(512 * 448) / 256, 256, 0, stream>>>(qw_v, qz_v, sc_v, Wh + (size_t)4096 * KD, 512);
    k_gemm_f16<<<dim3(NQKV / 128, Sq / 128, 1), 256, 0, stream>>>(Xh, Wh, biasc, Y, nullptr, Sq, NQKV, KD);
    k_rope2<<<Sq, 256, 0, stream>>>(Y, pos, Qhb, Qlb, Khb);
    k_vtrans<<<dim3(Sq / 64, 512 / 64), 256, 0, stream>>>(Y, Vt);
    k_dequant<<<(3584 * 448) / 256, 256, 0, stream>>>(qw_o, qz_o, sc_o, Wo, 3584);
    k_attn<<<dim3(768), 256, 0, stream>>>(Qhb, Qlb, Khb, Vt, AO, ctr);
    k_gemm_f16<<<dim3(Hdim / 128, Sq / 128, 2), 256, 0, stream>>>(AO, Wo, nullptr, out, Part, Sq, Hdim, KD);
    k_reduce<<<(Sq * Hdim / 4 + 255) / 256, 256, 0, stream>>>(out, Part, Sq * Hdim / 4);
}